// Round 1
// baseline (466.773 us; speedup 1.0000x reference)
//
#include <hip/hip_runtime.h>
#include <math.h>

#define EPS   1e-12f
#define NOW_T 3600.0f
#define TDEC  3600.0f
#define K     5
#define D     768

// ---------------------------------------------------------------------------
// Kernel 1: one wave per row (grid-stride). Computes
//   combined[i] = (0.5*cos_sim + 0.3/(1+dist) + 0.2*exp(-(NOW-t)/TDEC)) * strength
// Fully coalesced: lane reads float4 at column lane*4 + 256*j, j=0..2.
// ---------------------------------------------------------------------------
__global__ __launch_bounds__(256) void score_kernel(
    const float* __restrict__ q,      // [D]
    const float* __restrict__ loc,    // [2]
    const float* __restrict__ feat,   // [M][D]
    const float* __restrict__ mloc,   // [M][2]
    const float* __restrict__ meta,   // [M][4]
    float* __restrict__ scores,       // [M]  (workspace)
    int M)
{
    const int lane   = threadIdx.x & 63;
    const int wib    = threadIdx.x >> 6;
    const int wpb    = blockDim.x >> 6;
    const int gwave  = blockIdx.x * wpb + wib;
    const int nwaves = gridDim.x * wpb;

    // Query fragment in registers (12 floats/lane), matches feature columns.
    const int c = lane * 4;
    float4 q0 = *(const float4*)(q + c);
    float4 q1 = *(const float4*)(q + c + 256);
    float4 q2 = *(const float4*)(q + c + 512);

    // ||q||^2 via butterfly reduce (once per wave)
    float qss = q0.x*q0.x + q0.y*q0.y + q0.z*q0.z + q0.w*q0.w
              + q1.x*q1.x + q1.y*q1.y + q1.z*q1.z + q1.w*q1.w
              + q2.x*q2.x + q2.y*q2.y + q2.z*q2.z + q2.w*q2.w;
    #pragma unroll
    for (int m = 1; m < 64; m <<= 1) qss += __shfl_xor(qss, m);
    const float inv_qn = 1.0f / fmaxf(sqrtf(qss), EPS);

    const float lx = loc[0];
    const float ly = loc[1];

    for (int row = gwave; row < M; row += nwaves) {
        const float* r = feat + (size_t)row * D;
        float4 f0 = *(const float4*)(r + c);
        float4 f1 = *(const float4*)(r + c + 256);
        float4 f2 = *(const float4*)(r + c + 512);

        float dot = 0.f, ss = 0.f;
        dot = fmaf(f0.x, q0.x, dot); ss = fmaf(f0.x, f0.x, ss);
        dot = fmaf(f0.y, q0.y, dot); ss = fmaf(f0.y, f0.y, ss);
        dot = fmaf(f0.z, q0.z, dot); ss = fmaf(f0.z, f0.z, ss);
        dot = fmaf(f0.w, q0.w, dot); ss = fmaf(f0.w, f0.w, ss);
        dot = fmaf(f1.x, q1.x, dot); ss = fmaf(f1.x, f1.x, ss);
        dot = fmaf(f1.y, q1.y, dot); ss = fmaf(f1.y, f1.y, ss);
        dot = fmaf(f1.z, q1.z, dot); ss = fmaf(f1.z, f1.z, ss);
        dot = fmaf(f1.w, q1.w, dot); ss = fmaf(f1.w, f1.w, ss);
        dot = fmaf(f2.x, q2.x, dot); ss = fmaf(f2.x, f2.x, ss);
        dot = fmaf(f2.y, q2.y, dot); ss = fmaf(f2.y, f2.y, ss);
        dot = fmaf(f2.z, q2.z, dot); ss = fmaf(f2.z, f2.z, ss);
        dot = fmaf(f2.w, q2.w, dot); ss = fmaf(f2.w, f2.w, ss);

        #pragma unroll
        for (int m = 1; m < 64; m <<= 1) {
            dot += __shfl_xor(dot, m);
            ss  += __shfl_xor(ss,  m);
        }

        if (lane == 0) {
            float sim = dot * inv_qn / fmaxf(sqrtf(ss), EPS);
            float2 ml = *(const float2*)(mloc + (size_t)row * 2);
            float4 md = *(const float4*)(meta + (size_t)row * 4);
            float dx = ml.x - lx, dy = ml.y - ly;
            float dist = sqrtf(dx*dx + dy*dy);
            float spatial  = 1.0f / (1.0f + dist);
            float temporal = expf((md.y - NOW_T) / TDEC);
            scores[row] = (0.5f*sim + 0.3f*spatial + 0.2f*temporal) * md.x;
        }
    }
}

// ---------------------------------------------------------------------------
// Kernel 2: single-block top-K. Per-thread sorted top-5, then LDS tree merge.
// out[0..4] = scores (desc), out[5..9] = indices as float.
// ---------------------------------------------------------------------------
__global__ __launch_bounds__(1024) void topk_kernel(
    const float* __restrict__ scores, int M, float* __restrict__ out)
{
    __shared__ float s_val[1024 * K];
    __shared__ int   s_idx[1024 * K];

    const int tid = threadIdx.x;
    float v[K]; int ix[K];
    #pragma unroll
    for (int j = 0; j < K; ++j) { v[j] = -INFINITY; ix[j] = -1; }

    for (int i = tid; i < M; i += blockDim.x) {
        float s = scores[i];
        if (s > v[K-1]) {
            int j = K - 1;
            #pragma unroll
            for (int t = K - 1; t > 0; --t) {
                if (v[t-1] < s) { v[t] = v[t-1]; ix[t] = ix[t-1]; j = t - 1; }
            }
            v[j] = s; ix[j] = i;
        }
    }

    #pragma unroll
    for (int j = 0; j < K; ++j) { s_val[tid*K + j] = v[j]; s_idx[tid*K + j] = ix[j]; }
    __syncthreads();

    for (int sz = blockDim.x >> 1; sz >= 1; sz >>= 1) {
        if (tid < sz) {
            const float* pv = &s_val[(tid + sz) * K];
            const int*   pi = &s_idx[(tid + sz) * K];
            float mv[K]; int mi[K];
            int a = 0, b = 0;
            #pragma unroll
            for (int j = 0; j < K; ++j) {
                bool takeA = (b >= K) || (a < K && v[a] >= pv[b]);
                if (takeA) { mv[j] = v[a];  mi[j] = ix[a]; ++a; }
                else       { mv[j] = pv[b]; mi[j] = pi[b]; ++b; }
            }
            #pragma unroll
            for (int j = 0; j < K; ++j) {
                v[j] = mv[j]; ix[j] = mi[j];
                s_val[tid*K + j] = v[j]; s_idx[tid*K + j] = ix[j];
            }
        }
        __syncthreads();
    }

    if (tid == 0) {
        #pragma unroll
        for (int j = 0; j < K; ++j) {
            out[j]     = v[j];
            out[K + j] = (float)ix[j];
        }
    }
}

extern "C" void kernel_launch(void* const* d_in, const int* in_sizes, int n_in,
                              void* d_out, int out_size, void* d_ws, size_t ws_size,
                              hipStream_t stream) {
    const float* q    = (const float*)d_in[0];   // [768]
    const float* loc  = (const float*)d_in[1];   // [2]
    const float* feat = (const float*)d_in[2];   // [M*768]
    const float* mloc = (const float*)d_in[3];   // [M*2]
    const float* meta = (const float*)d_in[4];   // [M*4]
    const int M = in_sizes[2] / D;

    float* scores = (float*)d_ws;                // M floats = 400 KB

    score_kernel<<<2048, 256, 0, stream>>>(q, loc, feat, mloc, meta, scores, M);
    topk_kernel<<<1, 1024, 0, stream>>>(scores, M, (float*)d_out);
}

// Round 2
// 448.509 us; speedup vs baseline: 1.0407x; 1.0407x over previous
//
#include <hip/hip_runtime.h>
#include <math.h>

#define EPS   1e-12f
#define NOW_T 3600.0f
#define TDEC  3600.0f
#define K     5
#define D     768

// ---------------------------------------------------------------------------
// Kernel 1 v2: 16 lanes per row (quarter-wave group). Each lane issues 12
// independent float4 loads (192 B) -> high MLP; 4-step shuffle reduce.
// Block of 256 threads = 16 rows, no grid-stride loop. grid = ceil(M/16).
// ---------------------------------------------------------------------------
__global__ __launch_bounds__(256) void score_kernel(
    const float* __restrict__ q,      // [D]
    const float* __restrict__ loc,    // [2]
    const float* __restrict__ feat,   // [M][D]
    const float* __restrict__ mloc,   // [M][2]
    const float* __restrict__ meta,   // [M][4]
    float* __restrict__ scores,       // [M]  (workspace)
    int M)
{
    const int tid = threadIdx.x;
    const int c   = tid & 15;          // column lane within 16-lane group
    const int g   = tid >> 4;          // row group within block
    const int row = blockIdx.x * 16 + g;

    // q fragment: 48 floats/lane (group's 16 lanes cover all 768)
    const float* qp = q + c * 4;
    float4 qv[12];
    float qss = 0.f;
    #pragma unroll
    for (int j = 0; j < 12; ++j) {
        qv[j] = *(const float4*)(qp + j * 64);
        qss = fmaf(qv[j].x, qv[j].x, qss);
        qss = fmaf(qv[j].y, qv[j].y, qss);
        qss = fmaf(qv[j].z, qv[j].z, qss);
        qss = fmaf(qv[j].w, qv[j].w, qss);
    }
    #pragma unroll
    for (int m = 1; m < 16; m <<= 1) qss += __shfl_xor(qss, m);
    const float inv_qn = 1.0f / fmaxf(sqrtf(qss), EPS);

    float dot = 0.f, ss = 0.f;
    if (row < M) {
        const float* r = feat + (size_t)row * D + c * 4;
        #pragma unroll
        for (int j = 0; j < 12; ++j) {
            float4 f = *(const float4*)(r + j * 64);
            dot = fmaf(f.x, qv[j].x, dot); ss = fmaf(f.x, f.x, ss);
            dot = fmaf(f.y, qv[j].y, dot); ss = fmaf(f.y, f.y, ss);
            dot = fmaf(f.z, qv[j].z, dot); ss = fmaf(f.z, f.z, ss);
            dot = fmaf(f.w, qv[j].w, dot); ss = fmaf(f.w, f.w, ss);
        }
    }
    #pragma unroll
    for (int m = 1; m < 16; m <<= 1) {
        dot += __shfl_xor(dot, m);
        ss  += __shfl_xor(ss,  m);
    }

    if (row < M && c == 0) {
        float sim = dot * inv_qn / fmaxf(sqrtf(ss), EPS);
        float2 ml = *(const float2*)(mloc + (size_t)row * 2);
        float4 md = *(const float4*)(meta + (size_t)row * 4);
        float dx = ml.x - loc[0], dy = ml.y - loc[1];
        float dist = sqrtf(dx * dx + dy * dy);
        float spatial  = 1.0f / (1.0f + dist);
        float temporal = expf((md.y - NOW_T) / TDEC);
        scores[row] = (0.5f * sim + 0.3f * spatial + 0.2f * temporal) * md.x;
    }
}

// ---------------------------------------------------------------------------
// Kernel 2 v2: single-block top-K. float4 scan (4 scores/iter), per-thread
// sorted top-5, LDS tree merge. out[0..4]=scores, out[5..9]=indices (float).
// ---------------------------------------------------------------------------
__device__ __forceinline__ void consider(float (&v)[K], int (&ix)[K], float s, int i)
{
    if (s > v[K - 1]) {
        int j = K - 1;
        #pragma unroll
        for (int t = K - 1; t > 0; --t) {
            if (v[t - 1] < s) { v[t] = v[t - 1]; ix[t] = ix[t - 1]; j = t - 1; }
        }
        v[j] = s; ix[j] = i;
    }
}

__global__ __launch_bounds__(1024) void topk_kernel(
    const float* __restrict__ scores, int M, float* __restrict__ out)
{
    __shared__ float s_val[1024 * K];
    __shared__ int   s_idx[1024 * K];

    const int tid = threadIdx.x;
    float v[K]; int ix[K];
    #pragma unroll
    for (int j = 0; j < K; ++j) { v[j] = -INFINITY; ix[j] = -1; }

    const int M4 = M >> 2;
    const float4* s4 = (const float4*)scores;
    for (int i = tid; i < M4; i += 1024) {
        float4 s = s4[i];
        consider(v, ix, s.x, 4 * i + 0);
        consider(v, ix, s.y, 4 * i + 1);
        consider(v, ix, s.z, 4 * i + 2);
        consider(v, ix, s.w, 4 * i + 3);
    }
    for (int i = (M4 << 2) + tid; i < M; i += 1024)   // tail (M % 4)
        consider(v, ix, scores[i], i);

    #pragma unroll
    for (int j = 0; j < K; ++j) { s_val[tid * K + j] = v[j]; s_idx[tid * K + j] = ix[j]; }
    __syncthreads();

    for (int sz = 1024 >> 1; sz >= 1; sz >>= 1) {
        if (tid < sz) {
            const float* pv = &s_val[(tid + sz) * K];
            const int*   pi = &s_idx[(tid + sz) * K];
            float mv[K]; int mi[K];
            int a = 0, b = 0;
            #pragma unroll
            for (int j = 0; j < K; ++j) {
                bool takeA = (b >= K) || (a < K && v[a] >= pv[b]);
                if (takeA) { mv[j] = v[a];  mi[j] = ix[a]; ++a; }
                else       { mv[j] = pv[b]; mi[j] = pi[b]; ++b; }
            }
            #pragma unroll
            for (int j = 0; j < K; ++j) {
                v[j] = mv[j]; ix[j] = mi[j];
                s_val[tid * K + j] = v[j]; s_idx[tid * K + j] = ix[j];
            }
        }
        __syncthreads();
    }

    if (tid == 0) {
        #pragma unroll
        for (int j = 0; j < K; ++j) {
            out[j]     = v[j];
            out[K + j] = (float)ix[j];
        }
    }
}

extern "C" void kernel_launch(void* const* d_in, const int* in_sizes, int n_in,
                              void* d_out, int out_size, void* d_ws, size_t ws_size,
                              hipStream_t stream) {
    const float* q    = (const float*)d_in[0];   // [768]
    const float* loc  = (const float*)d_in[1];   // [2]
    const float* feat = (const float*)d_in[2];   // [M*768]
    const float* mloc = (const float*)d_in[3];   // [M*2]
    const float* meta = (const float*)d_in[4];   // [M*4]
    const int M = in_sizes[2] / D;

    float* scores = (float*)d_ws;                // M floats = 400 KB

    score_kernel<<<(M + 15) / 16, 256, 0, stream>>>(q, loc, feat, mloc, meta, scores, M);
    topk_kernel<<<1, 1024, 0, stream>>>(scores, M, (float*)d_out);
}

// Round 3
// 434.050 us; speedup vs baseline: 1.0754x; 1.0333x over previous
//
#include <hip/hip_runtime.h>
#include <math.h>

#define EPS   1e-12f
#define NOW_T 3600.0f
#define TDEC  3600.0f
#define K     5
#define D     768
#define GRID  2048   // 2048 blocks x 256 thr = 524288 = exact device thread capacity

__device__ __forceinline__ void consider(float (&v)[K], int (&ix)[K], float s, int i)
{
    if (s > v[K - 1]) {
        int j = K - 1;
        #pragma unroll
        for (int t = K - 1; t > 0; --t) {
            if (v[t - 1] < s) { v[t] = v[t - 1]; ix[t] = ix[t - 1]; j = t - 1; }
        }
        v[j] = s; ix[j] = i;
    }
}

// ---------------------------------------------------------------------------
// Fused kernel: 16 lanes per row, grid-stride over row chunks. Group leader
// (c==0) keeps a private sorted top-5; block epilogue merges 16 leaders' lists
// and writes one top-5 candidate set per block (no 400 KB score round-trip).
// ---------------------------------------------------------------------------
__global__ __launch_bounds__(256) void score_topk_kernel(
    const float* __restrict__ q,      // [D]
    const float* __restrict__ loc,    // [2]
    const float* __restrict__ feat,   // [M][D]
    const float* __restrict__ mloc,   // [M][2]
    const float* __restrict__ meta,   // [M][4]
    float* __restrict__ cand_val,     // [GRID*K]
    int*   __restrict__ cand_idx,     // [GRID*K]
    int M)
{
    const int tid = threadIdx.x;
    const int c   = tid & 15;          // lane within 16-lane row group
    const int g   = tid >> 4;          // row group within block (0..15)

    // Query fragment: 48 floats/lane (16 lanes cover all 768 columns)
    const float* qp = q + c * 4;
    float4 qv[12];
    float qss = 0.f;
    #pragma unroll
    for (int j = 0; j < 12; ++j) {
        qv[j] = *(const float4*)(qp + j * 64);
        qss = fmaf(qv[j].x, qv[j].x, qss);
        qss = fmaf(qv[j].y, qv[j].y, qss);
        qss = fmaf(qv[j].z, qv[j].z, qss);
        qss = fmaf(qv[j].w, qv[j].w, qss);
    }
    #pragma unroll
    for (int m = 1; m < 16; m <<= 1) qss += __shfl_xor(qss, m);
    const float inv_qn = 1.0f / fmaxf(sqrtf(qss), EPS);

    const float lx = loc[0];
    const float ly = loc[1];

    float v[K]; int ix[K];
    #pragma unroll
    for (int j = 0; j < K; ++j) { v[j] = -INFINITY; ix[j] = -1; }

    for (int base = blockIdx.x * 16; base < M; base += GRID * 16) {
        const int row = base + g;
        float dot = 0.f, ss = 0.f;
        if (row < M) {
            const float* r = feat + (size_t)row * D + c * 4;
            #pragma unroll
            for (int j = 0; j < 12; ++j) {
                float4 f = *(const float4*)(r + j * 64);
                dot = fmaf(f.x, qv[j].x, dot); ss = fmaf(f.x, f.x, ss);
                dot = fmaf(f.y, qv[j].y, dot); ss = fmaf(f.y, f.y, ss);
                dot = fmaf(f.z, qv[j].z, dot); ss = fmaf(f.z, f.z, ss);
                dot = fmaf(f.w, qv[j].w, dot); ss = fmaf(f.w, f.w, ss);
            }
        }
        #pragma unroll
        for (int m = 1; m < 16; m <<= 1) {
            dot += __shfl_xor(dot, m);
            ss  += __shfl_xor(ss,  m);
        }
        if (row < M && c == 0) {
            float sim = dot * inv_qn / fmaxf(sqrtf(ss), EPS);
            float2 ml = *(const float2*)(mloc + (size_t)row * 2);
            float4 md = *(const float4*)(meta + (size_t)row * 4);
            float dx = ml.x - lx, dy = ml.y - ly;
            float dist = sqrtf(dx * dx + dy * dy);
            float spatial  = 1.0f / (1.0f + dist);
            float temporal = expf((md.y - NOW_T) / TDEC);
            float s = (0.5f * sim + 0.3f * spatial + 0.2f * temporal) * md.x;
            consider(v, ix, s, row);
        }
    }

    // Block epilogue: gather 16 leaders' sorted top-5, serial merge by thread 0.
    __shared__ float sv[16 * K];
    __shared__ int   si[16 * K];
    if (c == 0) {
        #pragma unroll
        for (int j = 0; j < K; ++j) { sv[g * K + j] = v[j]; si[g * K + j] = ix[j]; }
    }
    __syncthreads();
    if (tid == 0) {
        float bv[K]; int bi[K];
        #pragma unroll
        for (int j = 0; j < K; ++j) { bv[j] = -INFINITY; bi[j] = -1; }
        for (int t = 0; t < 16 * K; ++t) consider(bv, bi, sv[t], si[t]);
        #pragma unroll
        for (int j = 0; j < K; ++j) {
            cand_val[blockIdx.x * K + j] = bv[j];
            cand_idx[blockIdx.x * K + j] = bi[j];
        }
    }
}

// ---------------------------------------------------------------------------
// Merge kernel: single block over GRID*K = 10240 candidates (L2-resident).
// out[0..4] = scores (desc), out[5..9] = indices as float.
// ---------------------------------------------------------------------------
__global__ __launch_bounds__(1024) void merge_kernel(
    const float* __restrict__ cand_val, const int* __restrict__ cand_idx,
    int N, float* __restrict__ out)
{
    __shared__ float s_val[1024 * K];
    __shared__ int   s_idx[1024 * K];

    const int tid = threadIdx.x;
    float v[K]; int ix[K];
    #pragma unroll
    for (int j = 0; j < K; ++j) { v[j] = -INFINITY; ix[j] = -1; }

    for (int i = tid; i < N; i += 1024)
        consider(v, ix, cand_val[i], cand_idx[i]);

    #pragma unroll
    for (int j = 0; j < K; ++j) { s_val[tid * K + j] = v[j]; s_idx[tid * K + j] = ix[j]; }
    __syncthreads();

    for (int sz = 1024 >> 1; sz >= 1; sz >>= 1) {
        if (tid < sz) {
            const float* pv = &s_val[(tid + sz) * K];
            const int*   pi = &s_idx[(tid + sz) * K];
            float mv[K]; int mi[K];
            int a = 0, b = 0;
            #pragma unroll
            for (int j = 0; j < K; ++j) {
                bool takeA = (b >= K) || (a < K && v[a] >= pv[b]);
                if (takeA) { mv[j] = v[a];  mi[j] = ix[a]; ++a; }
                else       { mv[j] = pv[b]; mi[j] = pi[b]; ++b; }
            }
            #pragma unroll
            for (int j = 0; j < K; ++j) {
                v[j] = mv[j]; ix[j] = mi[j];
                s_val[tid * K + j] = v[j]; s_idx[tid * K + j] = ix[j];
            }
        }
        __syncthreads();
    }

    if (tid == 0) {
        #pragma unroll
        for (int j = 0; j < K; ++j) {
            out[j]     = v[j];
            out[K + j] = (float)ix[j];
        }
    }
}

extern "C" void kernel_launch(void* const* d_in, const int* in_sizes, int n_in,
                              void* d_out, int out_size, void* d_ws, size_t ws_size,
                              hipStream_t stream) {
    const float* q    = (const float*)d_in[0];   // [768]
    const float* loc  = (const float*)d_in[1];   // [2]
    const float* feat = (const float*)d_in[2];   // [M*768]
    const float* mloc = (const float*)d_in[3];   // [M*2]
    const float* meta = (const float*)d_in[4];   // [M*4]
    const int M = in_sizes[2] / D;

    float* cand_val = (float*)d_ws;                      // GRID*K floats (40 KB)
    int*   cand_idx = (int*)((char*)d_ws + GRID * K * sizeof(float));

    score_topk_kernel<<<GRID, 256, 0, stream>>>(q, loc, feat, mloc, meta,
                                                cand_val, cand_idx, M);
    merge_kernel<<<1, 1024, 0, stream>>>(cand_val, cand_idx, GRID * K, (float*)d_out);
}